// Round 24
// baseline (144.696 us; speedup 1.0000x reference)
//
#include <hip/hip_runtime.h>

#define NVERT 40000

// R24 = R23 with the value-path t-accumulation FOLDED INTO the pass loop:
//   att = s[p]*rden and rden is scalar-common => accumulate t with
//   unnormalized s[p] in-pass, scale by rden after the denominator reduce.
// Wins: f never round-trips LDS (R22's value path re-read the lane's OWN
// fh -- pure spill-to-LDS: -4 b128 writes, -8 b128 reads, -1 fence), and
// the 24 pk_fma/pass fill the score-shuffle latency shadow (rs8+allreduce
// = ~6 serial shuffle rounds/pass that otherwise stall the wave).
// u0/u1 back in regs; sU dropped. Reg est ~95-105 < 128 cap (WRITE=verdict).
// LDS: sWqkH 2KB + sWvH 6KB + sF 16KB (ptm only) = 24KB.

typedef __fp16 hf2 __attribute__((ext_vector_type(2)));

__device__ __forceinline__ void wave_lds_fence() {
  asm volatile("s_waitcnt lgkmcnt(0)" ::: "memory");
}

__device__ __forceinline__ hf2 pk_h2(float a, float b) {
  return __builtin_amdgcn_cvt_pkrtz(a, b);
}
__device__ __forceinline__ unsigned int h2u(hf2 h) {
  unsigned int u; __builtin_memcpy(&u, &h, 4); return u;
}
__device__ __forceinline__ hf2 uh2(unsigned int u) {
  hf2 h; __builtin_memcpy(&h, &u, 4); return h;
}
__device__ __forceinline__ float fdot2(hf2 a, hf2 b, float c) {
#if __has_builtin(__builtin_amdgcn_fdot2)
  return __builtin_amdgcn_fdot2(a, b, c, false);
#else
  return (float)a.x * (float)b.x + (float)a.y * (float)b.y + c;
#endif
}

// reduce-scatter over c-lanes (xor 1,2,4): lane with octet-index c gets sum of v[c].
__device__ __forceinline__ float rs8(const float v[8], int c) {
  float snd, kp, s0, s1, s2, s3, t0, t1;
  snd = (c & 1) ? v[0] : v[1]; kp = (c & 1) ? v[1] : v[0]; s0 = kp + __shfl_xor(snd, 1);
  snd = (c & 1) ? v[2] : v[3]; kp = (c & 1) ? v[3] : v[2]; s1 = kp + __shfl_xor(snd, 1);
  snd = (c & 1) ? v[4] : v[5]; kp = (c & 1) ? v[5] : v[4]; s2 = kp + __shfl_xor(snd, 1);
  snd = (c & 1) ? v[6] : v[7]; kp = (c & 1) ? v[7] : v[6]; s3 = kp + __shfl_xor(snd, 1);
  snd = (c & 2) ? s0 : s1;     kp = (c & 2) ? s1 : s0;     t0 = kp + __shfl_xor(snd, 2);
  snd = (c & 2) ? s2 : s3;     kp = (c & 2) ? s3 : s2;     t1 = kp + __shfl_xor(snd, 2);
  snd = (c & 4) ? t0 : t1;     kp = (c & 4) ? t1 : t0;     return kp + __shfl_xor(snd, 4);
}

// reduce-scatter over n8-lanes (xor 8,16,32): lane with group-index n8 gets sum of v[n8].
__device__ __forceinline__ float rs8n(const float v[8], int n8) {
  float snd, kp, s0, s1, s2, s3, t0, t1;
  snd = (n8 & 1) ? v[0] : v[1]; kp = (n8 & 1) ? v[1] : v[0]; s0 = kp + __shfl_xor(snd, 8);
  snd = (n8 & 1) ? v[2] : v[3]; kp = (n8 & 1) ? v[3] : v[2]; s1 = kp + __shfl_xor(snd, 8);
  snd = (n8 & 1) ? v[4] : v[5]; kp = (n8 & 1) ? v[5] : v[4]; s2 = kp + __shfl_xor(snd, 8);
  snd = (n8 & 1) ? v[6] : v[7]; kp = (n8 & 1) ? v[7] : v[6]; s3 = kp + __shfl_xor(snd, 8);
  snd = (n8 & 2) ? s0 : s1;     kp = (n8 & 2) ? s1 : s0;     t0 = kp + __shfl_xor(snd, 16);
  snd = (n8 & 2) ? s2 : s3;     kp = (n8 & 2) ? s3 : s2;     t1 = kp + __shfl_xor(snd, 16);
  snd = (n8 & 4) ? t0 : t1;     kp = (n8 & 4) ? t1 : t0;     return kp + __shfl_xor(snd, 32);
}

__global__ __launch_bounds__(256, 2)
void ge_attn(const float* __restrict__ x,
             const int* __restrict__ nbr,
             const void* __restrict__ maskp,
             const float* __restrict__ ptm,
             const float* __restrict__ rpu,
             const float* __restrict__ rbasis,
             const float* __restrict__ qcoef,
             const float* __restrict__ kcoef,
             const float* __restrict__ vb0,
             const float* __restrict__ vb1,
             const float* __restrict__ vb2,
             const float* __restrict__ vp0,
             const float* __restrict__ vp1,
             const float* __restrict__ vp2,
             float* __restrict__ out)
{
  __shared__ __align__(16) unsigned int sWqkH[512];   // WQ rows(i*8+c) 4xh2 @0 | WK @256
  __shared__ __align__(16) unsigned int sWvH[1536];   // WV f16 i-pairs: o*256 + (i>>1)*64 + c*8 + n8
  __shared__ __align__(16) unsigned short sF[4][2048];// per-wave ptm f16, rows of 8 16B units
  __shared__ int sFlagB, sFlagF;

  const int tid = threadIdx.x;
  if (tid == 0) { sFlagB = 0; sFlagF = 0; }
  __syncthreads();

  // ---- mask dtype probe (bool bytes vs int32 vs float32), deterministic ----
  {
    const unsigned int* mw = (const unsigned int*)maskp;
    int b0 = 0, b1 = 0;
#pragma unroll
    for (int t = 0; t < 8; ++t) {
      const unsigned int w = mw[tid + (t << 8)];
      b1 |= (w == 0x3F800000u) ? 1 : 0;
      b0 |= (w > 1u && w != 0x3F800000u) ? 1 : 0;
    }
    if (b0) sFlagB = 1;
    if (b1) sFlagF = 1;
  }

  // ---- per-block W precompute into LDS ----
  for (int r = tid; r < 512; r += 256) {
    const int m = r >> 6;
    const int cc = (r >> 3) & 7;
    const int ii = r & 7;
    const float* par; const float* bas; int ospan, oo;
    switch (m) {
      case 0:  par = qcoef; bas = rbasis; ospan = 1; oo = 0; break;
      case 1:  par = kcoef; bas = rbasis; ospan = 1; oo = 0; break;
      case 2:  par = vp0;   bas = vb0;    ospan = 1; oo = 0; break;
      case 3:  par = vp1;   bas = vb1;    ospan = 2; oo = 0; break;
      case 4:  par = vp1;   bas = vb1;    ospan = 2; oo = 1; break;
      case 5:  par = vp2;   bas = vb2;    ospan = 3; oo = 0; break;
      case 6:  par = vp2;   bas = vb2;    ospan = 3; oo = 1; break;
      default: par = vp2;   bas = vb2;    ospan = 3; oo = 2; break;
    }
    float acc[8] = {0,0,0,0,0,0,0,0};
#pragma unroll
    for (int b = 0; b < 8; ++b) {
      const float cf = par[cc*8 + b];
      const float* row = bas + (((b*ospan + oo)*8 + ii) << 3);
#pragma unroll
      for (int j = 0; j < 8; ++j) acc[j] += cf * row[j];
    }
    if (m < 2) {
      unsigned int* dst = sWqkH + (m << 8) + (((ii << 3) + cc) << 2);
      uint4 w;
      w.x = h2u(pk_h2(acc[0], acc[1]));
      w.y = h2u(pk_h2(acc[2], acc[3]));
      w.z = h2u(pk_h2(acc[4], acc[5]));
      w.w = h2u(pk_h2(acc[6], acc[7]));
      *(uint4*)dst = w;
    } else {
      // WV_o f16 i-pair layout: ushort idx = word(o, ii>>1, cc, j)*2 + (ii&1)
      unsigned short* dstH = (unsigned short*)sWvH;
      const int o = m - 2;
#pragma unroll
      for (int j = 0; j < 8; ++j) {
        unsigned int hu = h2u(pk_h2(acc[j], acc[j]));
        dstH[(((o << 8) + ((ii >> 1) << 6) + (cc << 3) + j) << 1) | (ii & 1)] =
            (unsigned short)(hu & 0xFFFFu);
      }
    }
  }
  __syncthreads();   // only block-wide barrier

  const int mode = sFlagB ? 1 : (sFlagF ? 2 : 0);

  const int wv   = tid >> 6;
  const int lane = tid & 63;
  const int n8   = lane >> 3;
  const int c    = lane & 7;
  const int v    = (blockIdx.x << 2) + wv;
  unsigned short* sFw = sF[wv];

  // ---- early independent loads: nbr, mask (packed), u in regs ----
  int nbv[4];
  float u0[4], u1[4];
  int mkbits = 0;
#pragma unroll
  for (int p = 0; p < 4; ++p) {
    const int mi = (v << 5) + (p << 3) + n8;
    nbv[p] = nbr[mi];
    const float2 uu = *(const float2*)(rpu + ((size_t)mi << 1));
    u0[p] = uu.x; u1[p] = uu.y;
    int mk;
    if (mode == 1)      mk = ((const unsigned char*)maskp)[mi] != 0;
    else if (mode == 2) mk = ((((const unsigned int*)maskp)[mi]) & 0x7FFFFFFFu) != 0u;
    else                mk = ((const int*)maskp)[mi] != 0;
    mkbits |= (mk << p);
  }

  // ---- Q via packed-f16 dot2 + reduce-scatter ----
  float Q1;
  {
    const float* xq = x + ((size_t)v << 6) + (c << 3);
    const float4 qa = *(const float4*)xq;
    const float4 qb = *(const float4*)(xq + 4);
    hf2 xh0 = pk_h2(qa.x, qa.y), xh1 = pk_h2(qa.z, qa.w);
    hf2 xh2 = pk_h2(qb.x, qb.y), xh3 = pk_h2(qb.z, qb.w);
    float qp[8];
#pragma unroll
    for (int i = 0; i < 8; ++i) {
      const uint4 w = *(const uint4*)&sWqkH[((i << 3) + c) << 2];
      qp[i] = fdot2(uh2(w.w), xh3, fdot2(uh2(w.z), xh2,
              fdot2(uh2(w.y), xh1, fdot2(uh2(w.x), xh0, 0.0f))));
    }
    Q1 = rs8(qp, c);
  }

  // ---- stage ptm[v] into LDS as packed f16, swizzled units (unit = i^n8) ----
  {
    const float4* p4 = (const float4*)(ptm + (size_t)v * 2048);
#pragma unroll
    for (int t = 0; t < 8; ++t) {
      const int g = lane + (t << 6);
      const float4 val = p4[g];
      const int n  = g >> 4;
      const int ii = (g >> 1) & 7;
      const int hh = g & 1;
      const int unit = (n << 3) | (ii ^ (n & 7));
      *(uint2*)&sFw[(unit << 3) + (hh << 2)] =
          make_uint2(h2u(pk_h2(val.x, val.y)), h2u(pk_h2(val.z, val.w)));
    }
  }

  wave_lds_fence();   // staging complete before transport reads

  // ---- t accumulators (6 Taylor coefs x 4 f16-pair words), live across passes ----
  hf2 tp0[4], tp1[4], tp2[4], tp3[4], tp4[4], tp5[4];
#pragma unroll
  for (int q = 0; q < 4; ++q) {
    tp0[q] = uh2(0u); tp1[q] = uh2(0u); tp2[q] = uh2(0u);
    tp3[q] = uh2(0u); tp4[q] = uh2(0u); tp5[q] = uh2(0u);
  }

  // ---- passes: transport f, K, score, in-pass t-accumulation ----
  float s[4];
  const float* xb0 = x + ((size_t)nbv[0] << 6) + (c << 3);
  float4 xa = *(const float4*)xb0;
  float4 xc = *(const float4*)(xb0 + 4);
#pragma unroll
  for (int p = 0; p < 4; ++p) {
    float4 xan, xcn;
    if (p < 3) {
      const float* xbn = x + ((size_t)nbv[p + 1] << 6) + (c << 3);
      xan = *(const float4*)xbn;
      xcn = *(const float4*)(xbn + 4);
    }
    hf2 xh0 = pk_h2(xa.x, xa.y), xh1 = pk_h2(xa.z, xa.w);
    hf2 xh2 = pk_h2(xc.x, xc.y), xh3 = pk_h2(xc.z, xc.w);
    const int rowb = ((p << 3) + n8) << 3;
    // transport: pack fv pairwise as computed (2 transients + fh[4] live)
    hf2 fh0, fh1, fh2, fh3;
    float fprev;
#pragma unroll
    for (int i = 0; i < 8; ++i) {
      const uint4 r = *(const uint4*)&sFw[(rowb | (i ^ n8)) << 3];
      const float fcur =
          fdot2(uh2(r.w), xh3, fdot2(uh2(r.z), xh2,
          fdot2(uh2(r.y), xh1, fdot2(uh2(r.x), xh0, 0.0f))));
      if ((i & 1) == 0) {
        fprev = fcur;
      } else {
        const hf2 pk = pk_h2(fprev, fcur);
        if (i == 1) fh0 = pk;
        else if (i == 3) fh1 = pk;
        else if (i == 5) fh2 = pk;
        else fh3 = pk;
      }
    }
    float kp[8];
#pragma unroll
    for (int i = 0; i < 8; ++i) {
      const uint4 w = *(const uint4*)&sWqkH[256 + (((i << 3) + c) << 2)];
      kp[i] = fdot2(uh2(w.w), fh3, fdot2(uh2(w.z), fh2,
              fdot2(uh2(w.y), fh1, fdot2(uh2(w.x), fh0, 0.0f))));
    }
    const float K1 = rs8(kp, c);
    float sc = fmaxf(Q1 + K1, 0.0f);
    sc += __shfl_xor(sc, 1);
    sc += __shfl_xor(sc, 2);
    sc += __shfl_xor(sc, 4);
    const float sp = ((mkbits >> p) & 1) ? sc * 0.125f : 0.0f;
    s[p] = sp;

    // in-pass t-accumulation with UNNORMALIZED sp (rden applied later);
    // fills the shuffle-latency shadow; f never goes back to LDS.
    const float c1 = sp * u0[p], c2 = sp * u1[p];
    const float c3 = c1 * u0[p], c4 = 2.0f * c1 * u1[p], c5 = c2 * u1[p];
    const hf2 ch0 = pk_h2(sp, sp), ch1 = pk_h2(c1, c1), ch2 = pk_h2(c2, c2);
    const hf2 ch3 = pk_h2(c3, c3), ch4 = pk_h2(c4, c4), ch5 = pk_h2(c5, c5);
    tp0[0] += ch0*fh0; tp0[1] += ch0*fh1; tp0[2] += ch0*fh2; tp0[3] += ch0*fh3;
    tp1[0] += ch1*fh0; tp1[1] += ch1*fh1; tp1[2] += ch1*fh2; tp1[3] += ch1*fh3;
    tp2[0] += ch2*fh0; tp2[1] += ch2*fh1; tp2[2] += ch2*fh2; tp2[3] += ch2*fh3;
    tp3[0] += ch3*fh0; tp3[1] += ch3*fh1; tp3[2] += ch3*fh2; tp3[3] += ch3*fh3;
    tp4[0] += ch4*fh0; tp4[1] += ch4*fh1; tp4[2] += ch4*fh2; tp4[3] += ch4*fh3;
    tp5[0] += ch5*fh0; tp5[1] += ch5*fh1; tp5[2] += ch5*fh2; tp5[3] += ch5*fh3;

    if (p < 3) { xa = xan; xc = xcn; }
  }

  // ---- attention denominator (s[p] uniform across c within an n8 group) ----
  float dt = s[0] + s[1] + s[2] + s[3];
  dt += __shfl_xor(dt, 8);
  dt += __shfl_xor(dt, 16);
  dt += __shfl_xor(dt, 32);
  const float rden = 1.0f / fmaxf(dt, 1e-8f);

  // ---- value projection: h_o = rden * rs8n(t'_o); zp[q] += hh_o * WV word ----
  hf2 zp[4];
#pragma unroll
  for (int q = 0; q < 4; ++q) zp[q] = uh2(0u);
  const int wbase = (c << 3) + n8;

#define VAL_HALF(TPA, TPB, TPC, OB)                                          \
  {                                                                          \
    float t0[8], t1[8], t2[8];                                               \
    _Pragma("unroll")                                                        \
    for (int q = 0; q < 4; ++q) {                                            \
      t0[2*q] = (float)TPA[q].x; t0[2*q+1] = (float)TPA[q].y;                \
      t1[2*q] = (float)TPB[q].x; t1[2*q+1] = (float)TPB[q].y;                \
      t2[2*q] = (float)TPC[q].x; t2[2*q+1] = (float)TPC[q].y;                \
    }                                                                        \
    const float h0 = rden * rs8n(t0, n8);                                    \
    const float h1 = rden * rs8n(t1, n8);                                    \
    const float h2 = rden * rs8n(t2, n8);                                    \
    const hf2 hh0 = pk_h2(h0, h0), hh1 = pk_h2(h1, h1), hh2 = pk_h2(h2, h2); \
    _Pragma("unroll")                                                        \
    for (int q = 0; q < 4; ++q) {                                            \
      zp[q] += hh0 * uh2(sWvH[((OB + 0) << 8) + (q << 6) + wbase])           \
             + hh1 * uh2(sWvH[((OB + 1) << 8) + (q << 6) + wbase])           \
             + hh2 * uh2(sWvH[((OB + 2) << 8) + (q << 6) + wbase]);          \
    }                                                                        \
  }

  VAL_HALF(tp0, tp1, tp2, 0)
  VAL_HALF(tp3, tp4, tp5, 3)
#undef VAL_HALF

  float zacc[8];
#pragma unroll
  for (int q = 0; q < 4; ++q) {
    zacc[2*q]     = (float)zp[q].x;
    zacc[2*q + 1] = (float)zp[q].y;
  }
  const float outv = rs8n(zacc, n8);   // out[c, i=n8]
  out[((size_t)v << 6) + (c << 3) + n8] = outv;
}

extern "C" void kernel_launch(void* const* d_in, const int* in_sizes, int n_in,
                              void* d_out, int out_size, void* d_ws, size_t ws_size,
                              hipStream_t stream) {
  const float* x   = (const float*)d_in[0];
  const int*   nb  = (const int*)d_in[1];
  const void*  msk = d_in[2];
  const float* ptm = (const float*)d_in[3];
  const float* rpu = (const float*)d_in[4];
  const float* rb  = (const float*)d_in[5];
  const float* qc  = (const float*)d_in[6];
  const float* kc  = (const float*)d_in[7];
  const float* vb0 = (const float*)d_in[8];
  const float* vb1 = (const float*)d_in[9];
  const float* vb2 = (const float*)d_in[10];
  const float* vp0 = (const float*)d_in[11];
  const float* vp1 = (const float*)d_in[12];
  const float* vp2 = (const float*)d_in[13];
  (void)in_sizes; (void)n_in; (void)out_size; (void)d_ws; (void)ws_size;

  ge_attn<<<NVERT / 4, 256, 0, stream>>>(x, nb, msk, ptm, rpu, rb, qc, kc,
                                         vb0, vb1, vb2, vp0, vp1, vp2,
                                         (float*)d_out);
}

// Round 25
// 138.820 us; speedup vs baseline: 1.0423x; 1.0423x over previous
//
#include <hip/hip_runtime.h>

#define NVERT 40000

// FINAL (= R22, session best 138.8us): f16-dot2 everywhere, 128-VGPR cap.
// Ladder: 344 -> 307 -> 284 -> 186 -> 155 -> 139.6 -> 138.8 us.
// Converged: five orthogonal probes around this point (64-VGPR class R19,
// DS->reg shift R21, fence removal R23, in-pass t-fold R24) all null/worse.
// Constraint: ~2000 VALU inst/lane at 4 waves/SIMD (= (64,128] VGPR class cap)
// with ~30 serial shuffle rounds/wave -> ~47% issue efficiency; memory floor
// 50us unreachable without a different algorithm (shapes too small for MFMA).
// LDS: sWqkH 2KB + sWvH 6KB f16 + sF 16KB f16 + sU 1KB = ~25KB.

typedef __fp16 hf2 __attribute__((ext_vector_type(2)));

__device__ __forceinline__ void wave_lds_fence() {
  asm volatile("s_waitcnt lgkmcnt(0)" ::: "memory");
}
__device__ __forceinline__ void pass_sched_fence() {
  __builtin_amdgcn_sched_barrier(0x7);   // ALU may cross; VMEM/DS may not
}

__device__ __forceinline__ hf2 pk_h2(float a, float b) {
  return __builtin_amdgcn_cvt_pkrtz(a, b);
}
__device__ __forceinline__ unsigned int h2u(hf2 h) {
  unsigned int u; __builtin_memcpy(&u, &h, 4); return u;
}
__device__ __forceinline__ hf2 uh2(unsigned int u) {
  hf2 h; __builtin_memcpy(&h, &u, 4); return h;
}
__device__ __forceinline__ float fdot2(hf2 a, hf2 b, float c) {
#if __has_builtin(__builtin_amdgcn_fdot2)
  return __builtin_amdgcn_fdot2(a, b, c, false);
#else
  return (float)a.x * (float)b.x + (float)a.y * (float)b.y + c;
#endif
}

// reduce-scatter over c-lanes (xor 1,2,4): lane with octet-index c gets sum of v[c].
__device__ __forceinline__ float rs8(const float v[8], int c) {
  float snd, kp, s0, s1, s2, s3, t0, t1;
  snd = (c & 1) ? v[0] : v[1]; kp = (c & 1) ? v[1] : v[0]; s0 = kp + __shfl_xor(snd, 1);
  snd = (c & 1) ? v[2] : v[3]; kp = (c & 1) ? v[3] : v[2]; s1 = kp + __shfl_xor(snd, 1);
  snd = (c & 1) ? v[4] : v[5]; kp = (c & 1) ? v[5] : v[4]; s2 = kp + __shfl_xor(snd, 1);
  snd = (c & 1) ? v[6] : v[7]; kp = (c & 1) ? v[7] : v[6]; s3 = kp + __shfl_xor(snd, 1);
  snd = (c & 2) ? s0 : s1;     kp = (c & 2) ? s1 : s0;     t0 = kp + __shfl_xor(snd, 2);
  snd = (c & 2) ? s2 : s3;     kp = (c & 2) ? s3 : s2;     t1 = kp + __shfl_xor(snd, 2);
  snd = (c & 4) ? t0 : t1;     kp = (c & 4) ? t1 : t0;     return kp + __shfl_xor(snd, 4);
}

// reduce-scatter over n8-lanes (xor 8,16,32): lane with group-index n8 gets sum of v[n8].
__device__ __forceinline__ float rs8n(const float v[8], int n8) {
  float snd, kp, s0, s1, s2, s3, t0, t1;
  snd = (n8 & 1) ? v[0] : v[1]; kp = (n8 & 1) ? v[1] : v[0]; s0 = kp + __shfl_xor(snd, 8);
  snd = (n8 & 1) ? v[2] : v[3]; kp = (n8 & 1) ? v[3] : v[2]; s1 = kp + __shfl_xor(snd, 8);
  snd = (n8 & 1) ? v[4] : v[5]; kp = (n8 & 1) ? v[5] : v[4]; s2 = kp + __shfl_xor(snd, 8);
  snd = (n8 & 1) ? v[6] : v[7]; kp = (n8 & 1) ? v[7] : v[6]; s3 = kp + __shfl_xor(snd, 8);
  snd = (n8 & 2) ? s0 : s1;     kp = (n8 & 2) ? s1 : s0;     t0 = kp + __shfl_xor(snd, 16);
  snd = (n8 & 2) ? s2 : s3;     kp = (n8 & 2) ? s3 : s2;     t1 = kp + __shfl_xor(snd, 16);
  snd = (n8 & 4) ? t0 : t1;     kp = (n8 & 4) ? t1 : t0;     return kp + __shfl_xor(snd, 32);
}

__global__ __launch_bounds__(256, 2)
void ge_attn(const float* __restrict__ x,
             const int* __restrict__ nbr,
             const void* __restrict__ maskp,
             const float* __restrict__ ptm,
             const float* __restrict__ rpu,
             const float* __restrict__ rbasis,
             const float* __restrict__ qcoef,
             const float* __restrict__ kcoef,
             const float* __restrict__ vb0,
             const float* __restrict__ vb1,
             const float* __restrict__ vb2,
             const float* __restrict__ vp0,
             const float* __restrict__ vp1,
             const float* __restrict__ vp2,
             float* __restrict__ out)
{
  __shared__ __align__(16) unsigned int sWqkH[512];   // WQ rows(i*8+c) 4xh2 @0 | WK @256
  __shared__ __align__(16) unsigned int sWvH[1536];   // WV f16 i-pairs: o*256 + (i>>1)*64 + c*8 + n8
  __shared__ __align__(16) unsigned short sF[4][2048];// per-wave ptm/f f16, rows of 8 16B units
  __shared__ float sU[4][64];                         // per-wave u: (p*8+n8)*2 + {0,1}
  __shared__ int sFlagB, sFlagF;

  const int tid = threadIdx.x;
  if (tid == 0) { sFlagB = 0; sFlagF = 0; }
  __syncthreads();

  // ---- mask dtype probe (bool bytes vs int32 vs float32), deterministic ----
  {
    const unsigned int* mw = (const unsigned int*)maskp;
    int b0 = 0, b1 = 0;
#pragma unroll
    for (int t = 0; t < 8; ++t) {
      const unsigned int w = mw[tid + (t << 8)];
      b1 |= (w == 0x3F800000u) ? 1 : 0;
      b0 |= (w > 1u && w != 0x3F800000u) ? 1 : 0;
    }
    if (b0) sFlagB = 1;
    if (b1) sFlagF = 1;
  }

  // ---- per-block W precompute into LDS ----
  for (int r = tid; r < 512; r += 256) {
    const int m = r >> 6;
    const int cc = (r >> 3) & 7;
    const int ii = r & 7;
    const float* par; const float* bas; int ospan, oo;
    switch (m) {
      case 0:  par = qcoef; bas = rbasis; ospan = 1; oo = 0; break;
      case 1:  par = kcoef; bas = rbasis; ospan = 1; oo = 0; break;
      case 2:  par = vp0;   bas = vb0;    ospan = 1; oo = 0; break;
      case 3:  par = vp1;   bas = vb1;    ospan = 2; oo = 0; break;
      case 4:  par = vp1;   bas = vb1;    ospan = 2; oo = 1; break;
      case 5:  par = vp2;   bas = vb2;    ospan = 3; oo = 0; break;
      case 6:  par = vp2;   bas = vb2;    ospan = 3; oo = 1; break;
      default: par = vp2;   bas = vb2;    ospan = 3; oo = 2; break;
    }
    float acc[8] = {0,0,0,0,0,0,0,0};
#pragma unroll
    for (int b = 0; b < 8; ++b) {
      const float cf = par[cc*8 + b];
      const float* row = bas + (((b*ospan + oo)*8 + ii) << 3);
#pragma unroll
      for (int j = 0; j < 8; ++j) acc[j] += cf * row[j];
    }
    if (m < 2) {
      unsigned int* dst = sWqkH + (m << 8) + (((ii << 3) + cc) << 2);
      uint4 w;
      w.x = h2u(pk_h2(acc[0], acc[1]));
      w.y = h2u(pk_h2(acc[2], acc[3]));
      w.z = h2u(pk_h2(acc[4], acc[5]));
      w.w = h2u(pk_h2(acc[6], acc[7]));
      *(uint4*)dst = w;
    } else {
      // WV_o f16 i-pair layout: ushort idx = word(o, ii>>1, cc, j)*2 + (ii&1)
      unsigned short* dstH = (unsigned short*)sWvH;
      const int o = m - 2;
#pragma unroll
      for (int j = 0; j < 8; ++j) {
        unsigned int hu = h2u(pk_h2(acc[j], acc[j]));
        dstH[(((o << 8) + ((ii >> 1) << 6) + (cc << 3) + j) << 1) | (ii & 1)] =
            (unsigned short)(hu & 0xFFFFu);
      }
    }
  }
  __syncthreads();   // only block-wide barrier

  const int mode = sFlagB ? 1 : (sFlagF ? 2 : 0);

  const int wv   = tid >> 6;
  const int lane = tid & 63;
  const int n8   = lane >> 3;
  const int c    = lane & 7;
  const int v    = (blockIdx.x << 2) + wv;
  unsigned short* sFw = sF[wv];
  float* sUw = sU[wv];

  // ---- early independent loads: nbr, mask (packed), u -> LDS ----
  int nbv[4];
  int mkbits = 0;
#pragma unroll
  for (int p = 0; p < 4; ++p) {
    const int mi = (v << 5) + (p << 3) + n8;
    nbv[p] = nbr[mi];
    int mk;
    if (mode == 1)      mk = ((const unsigned char*)maskp)[mi] != 0;
    else if (mode == 2) mk = ((((const unsigned int*)maskp)[mi]) & 0x7FFFFFFFu) != 0u;
    else                mk = ((const int*)maskp)[mi] != 0;
    mkbits |= (mk << p);
  }
  if (c < 4) {   // lane handles p=c: one float2 per (p,n8)
    const int mi = (v << 5) + (c << 3) + n8;
    const float2 uu = *(const float2*)(rpu + ((size_t)mi << 1));
    *(float2*)&sUw[((c << 3) + n8) << 1] = uu;
  }

  // ---- Q via packed-f16 dot2 + reduce-scatter ----
  float Q1;
  {
    const float* xq = x + ((size_t)v << 6) + (c << 3);
    const float4 qa = *(const float4*)xq;
    const float4 qb = *(const float4*)(xq + 4);
    hf2 xh0 = pk_h2(qa.x, qa.y), xh1 = pk_h2(qa.z, qa.w);
    hf2 xh2 = pk_h2(qb.x, qb.y), xh3 = pk_h2(qb.z, qb.w);
    float qp[8];
#pragma unroll
    for (int i = 0; i < 8; ++i) {
      const uint4 w = *(const uint4*)&sWqkH[((i << 3) + c) << 2];
      qp[i] = fdot2(uh2(w.w), xh3, fdot2(uh2(w.z), xh2,
              fdot2(uh2(w.y), xh1, fdot2(uh2(w.x), xh0, 0.0f))));
    }
    Q1 = rs8(qp, c);
  }

  // ---- stage ptm[v] into LDS as packed f16, swizzled units (unit = i^n8) ----
  {
    const float4* p4 = (const float4*)(ptm + (size_t)v * 2048);
#pragma unroll
    for (int t = 0; t < 8; ++t) {
      const int g = lane + (t << 6);
      const float4 val = p4[g];
      const int n  = g >> 4;
      const int ii = (g >> 1) & 7;
      const int hh = g & 1;
      const int unit = (n << 3) | (ii ^ (n & 7));
      *(uint2*)&sFw[(unit << 3) + (hh << 2)] =
          make_uint2(h2u(pk_h2(val.x, val.y)), h2u(pk_h2(val.z, val.w)));
    }
  }

  wave_lds_fence();   // staging (and sU) complete before reads

  // ---- passes: transport f (dot2 from LDS f16), K (dot2 on packed f), score ----
  float s[4];
  const float* xb0 = x + ((size_t)nbv[0] << 6) + (c << 3);
  float4 xa = *(const float4*)xb0;
  float4 xc = *(const float4*)(xb0 + 4);
#pragma unroll
  for (int p = 0; p < 4; ++p) {
    float4 xan, xcn;
    if (p < 3) {
      const float* xbn = x + ((size_t)nbv[p + 1] << 6) + (c << 3);
      xan = *(const float4*)xbn;
      xcn = *(const float4*)(xbn + 4);
    }
    hf2 xh0 = pk_h2(xa.x, xa.y), xh1 = pk_h2(xa.z, xa.w);
    hf2 xh2 = pk_h2(xc.x, xc.y), xh3 = pk_h2(xc.z, xc.w);
    const int rowb = ((p << 3) + n8) << 3;
    // transport: pack fv pairwise as computed (2 transients + fh[4] live)
    hf2 fh0, fh1, fh2, fh3;
    float fprev;
#pragma unroll
    for (int i = 0; i < 8; ++i) {
      const uint4 r = *(const uint4*)&sFw[(rowb | (i ^ n8)) << 3];
      const float fcur =
          fdot2(uh2(r.w), xh3, fdot2(uh2(r.z), xh2,
          fdot2(uh2(r.y), xh1, fdot2(uh2(r.x), xh0, 0.0f))));
      if ((i & 1) == 0) {
        fprev = fcur;
      } else {
        const hf2 pk = pk_h2(fprev, fcur);
        if (i == 1) fh0 = pk;
        else if (i == 3) fh1 = pk;
        else if (i == 5) fh2 = pk;
        else fh3 = pk;
      }
    }
    float kp[8];
#pragma unroll
    for (int i = 0; i < 8; ++i) {
      const uint4 w = *(const uint4*)&sWqkH[256 + (((i << 3) + c) << 2)];
      kp[i] = fdot2(uh2(w.w), fh3, fdot2(uh2(w.z), fh2,
              fdot2(uh2(w.y), fh1, fdot2(uh2(w.x), fh0, 0.0f))));
    }
    const float K1 = rs8(kp, c);
    float sc = fmaxf(Q1 + K1, 0.0f);
    sc += __shfl_xor(sc, 1);
    sc += __shfl_xor(sc, 2);
    sc += __shfl_xor(sc, 4);
    s[p] = ((mkbits >> p) & 1) ? sc * 0.125f : 0.0f;

    *(uint4*)&sFw[(rowb | (c ^ n8)) << 3] =
        make_uint4(h2u(fh0), h2u(fh1), h2u(fh2), h2u(fh3));

    if (p < 3) { xa = xan; xc = xcn; }
    pass_sched_fence();
  }

  // ---- attention normalization ----
  float dt = s[0] + s[1] + s[2] + s[3];
  dt += __shfl_xor(dt, 8);
  dt += __shfl_xor(dt, 16);
  dt += __shfl_xor(dt, 32);
  const float rden = 1.0f / fmaxf(dt, 1e-8f);
#pragma unroll
  for (int p = 0; p < 4; ++p) s[p] *= rden;   // s[p] = att

  wave_lds_fence();   // f writes visible before value re-reads

  // ---- value path: packed-f16 accumulation + reduce-scatter ----
  hf2 zp[4];
#pragma unroll
  for (int q = 0; q < 4; ++q) zp[q] = uh2(0u);
#pragma unroll
  for (int hlf = 0; hlf < 2; ++hlf) {
    hf2 tp0[4], tp1[4], tp2[4];
#pragma unroll
    for (int q = 0; q < 4; ++q) { tp0[q] = uh2(0u); tp1[q] = uh2(0u); tp2[q] = uh2(0u); }
#pragma unroll
    for (int p = 0; p < 4; ++p) {
      const uint4 r = *(const uint4*)&sFw[(((((p << 3) + n8) << 3)) | (c ^ n8)) << 3];
      const hf2 f0 = uh2(r.x), f1 = uh2(r.y), f2 = uh2(r.z), f3 = uh2(r.w);
      const float2 uu = *(const float2*)&sUw[((p << 3) + n8) << 1];
      const float a = s[p];
      float cf0, cf1, cf2;
      if (hlf == 0) { cf0 = a;                  cf1 = a * uu.x;               cf2 = a * uu.y; }
      else          { cf0 = a * uu.x * uu.x;    cf1 = 2.0f * a * uu.x * uu.y; cf2 = a * uu.y * uu.y; }
      const hf2 ch0 = pk_h2(cf0, cf0), ch1 = pk_h2(cf1, cf1), ch2 = pk_h2(cf2, cf2);
      tp0[0] += ch0 * f0; tp0[1] += ch0 * f1; tp0[2] += ch0 * f2; tp0[3] += ch0 * f3;
      tp1[0] += ch1 * f0; tp1[1] += ch1 * f1; tp1[2] += ch1 * f2; tp1[3] += ch1 * f3;
      tp2[0] += ch2 * f0; tp2[1] += ch2 * f1; tp2[2] += ch2 * f2; tp2[3] += ch2 * f3;
    }
    // unpack once per half, reduce-scatter in f32
    float t0[8], t1[8], t2[8];
#pragma unroll
    for (int q = 0; q < 4; ++q) {
      t0[2*q] = (float)tp0[q].x; t0[2*q + 1] = (float)tp0[q].y;
      t1[2*q] = (float)tp1[q].x; t1[2*q + 1] = (float)tp1[q].y;
      t2[2*q] = (float)tp2[q].x; t2[2*q + 1] = (float)tp2[q].y;
    }
    const float h0 = rs8n(t0, n8);   // = h_{ob+0}[c, j=n8]
    const float h1 = rs8n(t1, n8);
    const float h2 = rs8n(t2, n8);
    const hf2 hh0 = pk_h2(h0, h0), hh1 = pk_h2(h1, h1), hh2 = pk_h2(h2, h2);
    const int ob = hlf * 3;
    const int wbase = (c << 3) + n8;
#pragma unroll
    for (int q = 0; q < 4; ++q) {
      zp[q] += hh0 * uh2(sWvH[((ob + 0) << 8) + (q << 6) + wbase])
             + hh1 * uh2(sWvH[((ob + 1) << 8) + (q << 6) + wbase])
             + hh2 * uh2(sWvH[((ob + 2) << 8) + (q << 6) + wbase]);
    }
  }
  float zacc[8];
#pragma unroll
  for (int q = 0; q < 4; ++q) {
    zacc[2*q]     = (float)zp[q].x;
    zacc[2*q + 1] = (float)zp[q].y;
  }
  const float outv = rs8n(zacc, n8);   // out[c, i=n8]
  out[((size_t)v << 6) + (c << 3) + n8] = outv;
}

extern "C" void kernel_launch(void* const* d_in, const int* in_sizes, int n_in,
                              void* d_out, int out_size, void* d_ws, size_t ws_size,
                              hipStream_t stream) {
  const float* x   = (const float*)d_in[0];
  const int*   nb  = (const int*)d_in[1];
  const void*  msk = d_in[2];
  const float* ptm = (const float*)d_in[3];
  const float* rpu = (const float*)d_in[4];
  const float* rb  = (const float*)d_in[5];
  const float* qc  = (const float*)d_in[6];
  const float* kc  = (const float*)d_in[7];
  const float* vb0 = (const float*)d_in[8];
  const float* vb1 = (const float*)d_in[9];
  const float* vb2 = (const float*)d_in[10];
  const float* vp0 = (const float*)d_in[11];
  const float* vp1 = (const float*)d_in[12];
  const float* vp2 = (const float*)d_in[13];
  (void)in_sizes; (void)n_in; (void)out_size; (void)d_ws; (void)ws_size;

  ge_attn<<<NVERT / 4, 256, 0, stream>>>(x, nb, msk, ptm, rpu, rb, qc, kc,
                                         vb0, vb1, vb2, vp0, vp1, vp2,
                                         (float*)d_out);
}